// Round 5
// baseline (154.135 us; speedup 1.0000x reference)
//
#include <hip/hip_runtime.h>
#include <math.h>

// Problem: B=4,S=2048,D=2048,E=64,K=2 -> tokens 8192, K-dim 2048, experts 64
// DIAGNOSTIC ROUND: 256 blocks x 2 sequential token-groups. Same total work
// and per-token numerics as the verified round-3 kernel; the single gate
// dispatch (~2x duration) rises above the ~41us harness fills into rocprof's
// top-5 so we finally see its true counters (VGPR/Occ/MfmaUtil/VALU/FETCH).
#define NTOK 8192
#define DDIM 2048
#define NEXP 64
#define MT   16            // tokens per group (MFMA M)
#define NGRP 2             // token-groups per block (sequential)
#define ASTR 72            // staged-row stride in halves (64 data + 8 pad)
#define CSTR 68            // partial-buffer row stride (floats)

#define GATED_SZ (NTOK * NEXP)
#define IDX_OFF  GATED_SZ
#define VALS_OFF (GATED_SZ + NTOK * 2)

#define NKSTEP (DDIM / 32)            // 64 MFMA k-steps
#define NTILE  (NEXP / 16)            // 4 n-tiles
#define BFRAG_HALVES ((size_t)NKSTEP * NTILE * 64 * 8)   // 131072 halves

typedef _Float16 f16x8 __attribute__((ext_vector_type(8)));
typedef _Float16 f16x4 __attribute__((ext_vector_type(4)));
typedef float    f32x4 __attribute__((ext_vector_type(4)));

// ---------------------------------------------------------------------------
// Pack W [E=64][D=2048] into MFMA B-fragments (fp16 hi + 4096-scaled lo).
// Frag (ks, nt): lane holds B[k=ks*32+(lane>>4)*8+j][n=nt*16+(lane&15)].
// Layout: Bh[((ks*4+nt)*64+lane)*8 + j]. (Verified absmax-stable.)
// ---------------------------------------------------------------------------
__global__ void pack_b_kernel(const float* __restrict__ W,
                              _Float16* __restrict__ Bh,
                              _Float16* __restrict__ Bl)
{
    const int tid  = blockIdx.x * blockDim.x + threadIdx.x;  // 0..16383
    const int lane = tid & 63;
    const int fid  = tid >> 6;
    const int ks   = fid >> 2;
    const int nt   = fid & 3;
    const int e    = nt * 16 + (lane & 15);
    const int k    = ks * 32 + (lane >> 4) * 8;
    const float* src = W + (size_t)e * DDIM + k;

    f16x8 hi, lo;
#pragma unroll
    for (int j = 0; j < 8; ++j) {
        const float v = src[j];
        const _Float16 h = (_Float16)v;
        hi[j] = h;
        lo[j] = (_Float16)((v - (float)h) * 4096.f);
    }
    *(f16x8*)(Bh + (size_t)tid * 8) = hi;
    *(f16x8*)(Bl + (size_t)tid * 8) = lo;
}

#define BFRAG(base, ks, nt) \
    (*(const f16x8*)((base) + ((((size_t)(ks)) * 4 + (nt)) * 64 + lane) * 8))

// fp32x4 -> fp16 hi + 4096-scaled lo residual (same split as pack_b).
static __device__ __forceinline__ void cvt_hilo4(float4 v, f16x4& h4, f16x4& l4)
{
    const float vv[4] = {v.x, v.y, v.z, v.w};
#pragma unroll
    for (int j = 0; j < 4; ++j) {
        const _Float16 hh = (_Float16)vv[j];
        h4[j] = hh;
        l4[j] = (_Float16)((vv[j] - (float)hh) * 4096.f);
    }
}

// ---------------------------------------------------------------------------
// Fused gate kernel. 256 blocks x 512 thr (8 waves); each block runs NGRP=2
// token-groups back-to-back. Per group: the round-3 verified pipeline --
// barrier-free main loop, wave w owns k-slice [w*256,w*256+256) of 16 tokens
// x 64 experts, per-wave private LDS staging (in-order ds ops), 4 sub-chunks
// of 64k with depth-2 register prefetch, then the 2-barrier cbuf epilogue
// (noise, top-2, softmax). A trailing barrier per group protects the
// cbuf/staging LDS alias across groups. Group 2 re-reads Bh/Bl L1/L2-warm.
// logits = acc_hh + 2^-12 * acc_lo (x_lo, w_lo pre-scaled by 4096).
// ---------------------------------------------------------------------------
__global__ __launch_bounds__(512, 4) void gate_kernel(
    const float* __restrict__ x,
    const _Float16* __restrict__ Bh,
    const _Float16* __restrict__ Bl,
    const float* __restrict__ noise_w,
    const float* __restrict__ noise,
    float* __restrict__ out)
{
    // per-wave staging: [hi|lo] x 16 rows x ASTR halves = 4608 B; x8 waves
    // = 36864 B. cbuf (34816 B) aliases this region after the barrier.
    __shared__ __align__(16) char smem_raw[8 * 2 * MT * ASTR * 2];

    const int tid  = threadIdx.x;
    const int lane = tid & 63;
    const int w    = __builtin_amdgcn_readfirstlane(tid >> 6);  // k-slice id
    const int q = lane >> 4;               // 0..3
    const int m = lane & 15;               // 0..15

    _Float16* xs = (_Float16*)smem_raw + (size_t)w * (2 * MT * ASTR);
    const float nwv = noise_w[lane];

    // Sub-chunk = 64 k. Piece p: lane covers row p*4+q, floats m*4..m*4+3.
#define LOADSUB(buf, s)                                                      \
    _Pragma("unroll")                                                        \
    for (int p = 0; p < 4; ++p) {                                            \
        buf[p] = *(const float4*)(xw + (size_t)(p * 4 + q) * DDIM            \
                                  + (s) * 64 + m * 4);                       \
    }

#define STAGESUB(buf)                                                        \
    _Pragma("unroll")                                                        \
    for (int p = 0; p < 4; ++p) {                                            \
        f16x4 h4, l4;                                                        \
        cvt_hilo4(buf[p], h4, l4);                                           \
        const int off = (p * 4 + q) * ASTR + m * 4;                          \
        *(f16x4*)&xs[off] = h4;                                              \
        *(f16x4*)&xs[MT * ASTR + off] = l4;                                  \
    }

    // k-step stp within sub-chunk s: global ks = w*8 + s*2 + stp
#define COMPUTESUB(s)                                                        \
    _Pragma("unroll")                                                        \
    for (int stp = 0; stp < 2; ++stp) {                                      \
        const int ks = w * 8 + (s) * 2 + stp;                                \
        const f16x8 ah = *(const f16x8*)&xs[m * ASTR + stp * 32 + q * 8];    \
        const f16x8 al = *(const f16x8*)&xs[MT * ASTR + m * ASTR + stp * 32 + q * 8]; \
        _Pragma("unroll")                                                    \
        for (int nt = 0; nt < 4; ++nt) {                                     \
            const f16x8 bh = BFRAG(Bh, ks, nt);                              \
            const f16x8 bl = BFRAG(Bl, ks, nt);                              \
            acc_hh[nt] = __builtin_amdgcn_mfma_f32_16x16x32_f16(ah, bh, acc_hh[nt], 0, 0, 0); \
            acc_lo[nt] = __builtin_amdgcn_mfma_f32_16x16x32_f16(ah, bl, acc_lo[nt], 0, 0, 0); \
            acc_lo[nt] = __builtin_amdgcn_mfma_f32_16x16x32_f16(al, bh, acc_lo[nt], 0, 0, 0); \
        }                                                                    \
    }

    for (int g = 0; g < NGRP; ++g) {
        const int tokBase = (blockIdx.x * NGRP + g) * MT;

        // wave's x window: 16 tokens x 256 k starting at w*256
        const float* xw = x + (size_t)tokBase * DDIM + (size_t)w * 256;

        // hoisted epilogue operands for this group
        const float nz0 = noise[(size_t)(tokBase + w * 2)     * NEXP + lane];
        const float nz1 = noise[(size_t)(tokBase + w * 2 + 1) * NEXP + lane];

        f32x4 acc_hh[4], acc_lo[4];
#pragma unroll
        for (int nt = 0; nt < 4; ++nt) {
            acc_hh[nt] = (f32x4){0.f, 0.f, 0.f, 0.f};
            acc_lo[nt] = (f32x4){0.f, 0.f, 0.f, 0.f};
        }

        float4 rA[4], rB[4];
        LOADSUB(rA, 0)      // depth-2 pipeline: two sub-chunks in flight
        LOADSUB(rB, 1)
        STAGESUB(rA)        // waits rA only; rB stays in flight
        LOADSUB(rA, 2)
        COMPUTESUB(0)       // per-wave in-order LDS ordering (verified)
        STAGESUB(rB)
        LOADSUB(rB, 3)
        COMPUTESUB(1)
        STAGESUB(rA)
        COMPUTESUB(2)
        STAGESUB(rB)
        COMPUTESUB(3)

        // ---- epilogue: 8 k-slice partials -> cbuf (aliases staging) ----
        __syncthreads();    // all waves done reading their staging regions
        float* cbuf = (float*)smem_raw;   // [8 partials][16 tokens][CSTR]

        // C/D layout: col(e)=lane&15, row(t)=q*4+r
#pragma unroll
        for (int nt = 0; nt < 4; ++nt) {
            const int e = nt * 16 + m;
#pragma unroll
            for (int r = 0; r < 4; ++r) {
                const int t = q * 4 + r;
                cbuf[((w * MT) + t) * CSTR + e] =
                    acc_hh[nt][r] + acc_lo[nt][r] * (1.f / 4096.f);
            }
        }
        __syncthreads();

        // Epilogue: wave w owns tokens w*2, w*2+1; lane = expert.
#pragma unroll
        for (int i = 0; i < 2; ++i) {
            const int t   = w * 2 + i;
            const int tok = tokBase + t;
            const int e   = lane;

            float v = 0.f;
#pragma unroll
            for (int p = 0; p < 8; ++p)
                v += cbuf[((p * MT) + t) * CSTR + e];
            v += (i ? nz1 : nz0) * nwv;

            // top-1: butterfly max, lax.top_k tie-break (lower index wins)
            float m1 = v; int i1 = e;
#pragma unroll
            for (int sh = 32; sh > 0; sh >>= 1) {
                float ov = __shfl_xor(m1, sh, 64);
                int   oi = __shfl_xor(i1, sh, 64);
                if (ov > m1 || (ov == m1 && oi < i1)) { m1 = ov; i1 = oi; }
            }
            float vm = (e == i1) ? -INFINITY : v;
            float m2 = vm; int i2 = e;
#pragma unroll
            for (int sh = 32; sh > 0; sh >>= 1) {
                float ov = __shfl_xor(m2, sh, 64);
                int   oi = __shfl_xor(i2, sh, 64);
                if (ov > m2 || (ov == m2 && oi < i2)) { m2 = ov; i2 = oi; }
            }

            const float e2  = expf(m2 - m1);
            const float inv = 1.f / (1.f + e2);
            const float p1  = inv;
            const float p2  = e2 * inv;

            float gval = 0.f;
            if (e == i1) gval = p1;
            else if (e == i2) gval = p2;
            out[(size_t)tok * NEXP + e] = gval;

            if (lane == 0) {
                out[IDX_OFF  + tok * 2 + 0] = (float)i1;
                out[IDX_OFF  + tok * 2 + 1] = (float)i2;
                out[VALS_OFF + tok * 2 + 0] = m1;
                out[VALS_OFF + tok * 2 + 1] = m2;
            }
        }

        __syncthreads();    // epilogue cbuf reads done before next group's
                            // staging writes (cbuf aliases staging LDS)
    }

#undef LOADSUB
#undef STAGESUB
#undef COMPUTESUB
}

extern "C" void kernel_launch(void* const* d_in, const int* in_sizes, int n_in,
                              void* d_out, int out_size, void* d_ws, size_t ws_size,
                              hipStream_t stream) {
    const float* x     = (const float*)d_in[0];
    const float* W     = (const float*)d_in[1];
    const float* nw    = (const float*)d_in[2];
    const float* noise = (const float*)d_in[3];
    // d_in[4] is k==2, hardcoded
    float* out = (float*)d_out;

    _Float16* Bh = (_Float16*)d_ws;                 // 256 KB
    _Float16* Bl = Bh + BFRAG_HALVES;               // 256 KB

    hipLaunchKernelGGL(pack_b_kernel, dim3(64), dim3(256), 0, stream, W, Bh, Bl);

    hipLaunchKernelGGL(gate_kernel, dim3(NTOK / (MT * NGRP)), dim3(512), 0,
                       stream, x, Bh, Bl, nw, noise, out);
}

// Round 6
// 112.500 us; speedup vs baseline: 1.3701x; 1.3701x over previous
//
#include <hip/hip_runtime.h>
#include <math.h>

// Problem: B=4,S=2048,D=2048,E=64,K=2 -> tokens 8192, K-dim 2048, experts 64
#define NTOK 8192
#define DDIM 2048
#define NEXP 64
#define MT   16            // tokens per block (MFMA M)
#define ASTR 72            // staged-row stride in halves (64 data + 8 pad)
#define CSTR 68            // partial-buffer row stride (floats)

#define GATED_SZ (NTOK * NEXP)
#define IDX_OFF  GATED_SZ
#define VALS_OFF (GATED_SZ + NTOK * 2)

#define NKSTEP (DDIM / 32)            // 64 MFMA k-steps
#define NTILE  (NEXP / 16)            // 4 n-tiles
#define BFRAG_HALVES ((size_t)NKSTEP * NTILE * 64 * 8)   // 131072 halves

typedef _Float16 f16x8 __attribute__((ext_vector_type(8)));
typedef _Float16 f16x4 __attribute__((ext_vector_type(4)));
typedef float    f32x4 __attribute__((ext_vector_type(4)));

// ---------------------------------------------------------------------------
// Pack W [E=64][D=2048] into MFMA B-fragments (fp16 hi + 4096-scaled lo).
// Frag (ks, nt): lane holds B[k=ks*32+(lane>>4)*8+j][n=nt*16+(lane&15)].
// Layout: Bh[((ks*4+nt)*64+lane)*8 + j]. (Verified absmax-stable.)
// ---------------------------------------------------------------------------
__global__ void pack_b_kernel(const float* __restrict__ W,
                              _Float16* __restrict__ Bh,
                              _Float16* __restrict__ Bl)
{
    const int tid  = blockIdx.x * blockDim.x + threadIdx.x;  // 0..16383
    const int lane = tid & 63;
    const int fid  = tid >> 6;
    const int ks   = fid >> 2;
    const int nt   = fid & 3;
    const int e    = nt * 16 + (lane & 15);
    const int k    = ks * 32 + (lane >> 4) * 8;
    const float* src = W + (size_t)e * DDIM + k;

    f16x8 hi, lo;
#pragma unroll
    for (int j = 0; j < 8; ++j) {
        const float v = src[j];
        const _Float16 h = (_Float16)v;
        hi[j] = h;
        lo[j] = (_Float16)((v - (float)h) * 4096.f);
    }
    *(f16x8*)(Bh + (size_t)tid * 8) = hi;
    *(f16x8*)(Bl + (size_t)tid * 8) = lo;
}

#define BFRAG(base, ks, nt) \
    (*(const f16x8*)((base) + ((((size_t)(ks)) * 4 + (nt)) * 64 + lane) * 8))

// fp32x4 -> fp16 hi + 4096-scaled lo residual (same split as pack_b).
static __device__ __forceinline__ void cvt_hilo4(float4 v, f16x4& h4, f16x4& l4)
{
    const float vv[4] = {v.x, v.y, v.z, v.w};
#pragma unroll
    for (int j = 0; j < 4; ++j) {
        const _Float16 hh = (_Float16)vv[j];
        h4[j] = hh;
        l4[j] = (_Float16)((vv[j] - (float)hh) * 4096.f);
    }
}

// ---------------------------------------------------------------------------
// Fused gate kernel. 512 blocks x 512 thr (8 waves). Wave w owns k-slice
// [w*256, w*256+256) of 16 tokens x 64 experts; barrier-free main loop with
// per-wave private LDS staging (in-order per-wave ds ops; absmax=0.0 for 4
// rounds). ROUND-6 CHANGE (one variable): the wave's ENTIRE 16 KB x-slice
// is issued as 16 independent float4 loads UP FRONT (64 VGPRs), drained
// sub-chunk-by-sub-chunk via the compiler's counted vmcnt(N) -- no barrier
// in the loop, so nothing drains vmcnt to 0. Exposed x-latency waits per
// group: ~4 (rounds 3/5, measured 35.5 us/group, MfmaUtil 3%) -> 1.
// While one wave waits, 8 waves x 16 KB = 128 KB outstanding per CU keeps
// the HBM queue full. Numerics/accumulation order bit-identical to round 3.
// logits = acc_hh + 2^-12 * acc_lo (x_lo, w_lo pre-scaled by 4096).
// ---------------------------------------------------------------------------
__global__ __launch_bounds__(512, 2) void gate_kernel(
    const float* __restrict__ x,
    const _Float16* __restrict__ Bh,
    const _Float16* __restrict__ Bl,
    const float* __restrict__ noise_w,
    const float* __restrict__ noise,
    float* __restrict__ out)
{
    // per-wave staging: [hi|lo] x 16 rows x ASTR halves = 4608 B; x8 waves
    // = 36864 B. cbuf (34816 B) aliases this region after the barrier.
    __shared__ __align__(16) char smem_raw[8 * 2 * MT * ASTR * 2];

    const int tid  = threadIdx.x;
    const int lane = tid & 63;
    const int w    = __builtin_amdgcn_readfirstlane(tid >> 6);  // k-slice id
    const int tokBase = blockIdx.x * MT;

    const int q = lane >> 4;               // 0..3
    const int m = lane & 15;               // 0..15

    _Float16* xs = (_Float16*)smem_raw + (size_t)w * (2 * MT * ASTR);

    // wave's x window: 16 tokens x 256 k starting at w*256
    const float* xw = x + (size_t)tokBase * DDIM + (size_t)w * 256;

    // ---- issue the FULL x-slice: 16 float4 loads, all independent ----
    // sub-chunk s, piece p: lane covers row p*4+q, floats s*64 + m*4..+3
    // (16 lanes span one contiguous 256B row segment -> coalesced).
    float4 xr[4][4];                       // [sub-chunk][piece], static idx
#pragma unroll
    for (int s = 0; s < 4; ++s)
#pragma unroll
        for (int p = 0; p < 4; ++p)
            xr[s][p] = *(const float4*)(xw + (size_t)(p * 4 + q) * DDIM
                                        + s * 64 + m * 4);

    // hoisted epilogue operands (issued after x so x loads are oldest)
    const float nwv = noise_w[lane];
    const float nz0 = noise[(size_t)(tokBase + w * 2)     * NEXP + lane];
    const float nz1 = noise[(size_t)(tokBase + w * 2 + 1) * NEXP + lane];

    f32x4 acc_hh[4], acc_lo[4];
#pragma unroll
    for (int nt = 0; nt < 4; ++nt) {
        acc_hh[nt] = (f32x4){0.f, 0.f, 0.f, 0.f};
        acc_lo[nt] = (f32x4){0.f, 0.f, 0.f, 0.f};
    }

    // drain: per sub-chunk, cvt+stage (waits only that sub-chunk's 4 loads
    // via counted vmcnt), then compute. Per-wave in-order DS ops make the
    // single-buffer reuse safe (reads of sc s retire before writes of s+1).
#pragma unroll
    for (int s = 0; s < 4; ++s) {
        // ---- stage sub-chunk s ----
#pragma unroll
        for (int p = 0; p < 4; ++p) {
            f16x4 h4, l4;
            cvt_hilo4(xr[s][p], h4, l4);
            const int off = (p * 4 + q) * ASTR + m * 4;
            *(f16x4*)&xs[off] = h4;
            *(f16x4*)&xs[MT * ASTR + off] = l4;
        }
        // ---- compute sub-chunk s: ks = w*8 + s*2 + stp ----
#pragma unroll
        for (int stp = 0; stp < 2; ++stp) {
            const int ks = w * 8 + s * 2 + stp;
            const f16x8 ah = *(const f16x8*)&xs[m * ASTR + stp * 32 + q * 8];
            const f16x8 al = *(const f16x8*)&xs[MT * ASTR + m * ASTR + stp * 32 + q * 8];
#pragma unroll
            for (int nt = 0; nt < 4; ++nt) {
                const f16x8 bh = BFRAG(Bh, ks, nt);
                const f16x8 bl = BFRAG(Bl, ks, nt);
                acc_hh[nt] = __builtin_amdgcn_mfma_f32_16x16x32_f16(ah, bh, acc_hh[nt], 0, 0, 0);
                acc_lo[nt] = __builtin_amdgcn_mfma_f32_16x16x32_f16(ah, bl, acc_lo[nt], 0, 0, 0);
                acc_lo[nt] = __builtin_amdgcn_mfma_f32_16x16x32_f16(al, bh, acc_lo[nt], 0, 0, 0);
            }
        }
    }

    // ---- epilogue: 8 k-slice partials -> cbuf (aliases staging LDS) ----
    __syncthreads();    // all waves done reading their staging regions
    float* cbuf = (float*)smem_raw;   // [8 partials][16 tokens][CSTR]

    // C/D layout: col(e)=lane&15, row(t)=q*4+r
#pragma unroll
    for (int nt = 0; nt < 4; ++nt) {
        const int e = nt * 16 + m;
#pragma unroll
        for (int r = 0; r < 4; ++r) {
            const int t = q * 4 + r;
            cbuf[((w * MT) + t) * CSTR + e] =
                acc_hh[nt][r] + acc_lo[nt][r] * (1.f / 4096.f);
        }
    }
    __syncthreads();

    // Epilogue: wave w owns tokens w*2, w*2+1; lane = expert.
#pragma unroll
    for (int i = 0; i < 2; ++i) {
        const int t   = w * 2 + i;
        const int tok = tokBase + t;
        const int e   = lane;

        float v = 0.f;
#pragma unroll
        for (int p = 0; p < 8; ++p)
            v += cbuf[((p * MT) + t) * CSTR + e];
        v += (i ? nz1 : nz0) * nwv;

        // top-1: butterfly max, lax.top_k tie-break (lower index wins)
        float m1 = v; int i1 = e;
#pragma unroll
        for (int sh = 32; sh > 0; sh >>= 1) {
            float ov = __shfl_xor(m1, sh, 64);
            int   oi = __shfl_xor(i1, sh, 64);
            if (ov > m1 || (ov == m1 && oi < i1)) { m1 = ov; i1 = oi; }
        }
        float vm = (e == i1) ? -INFINITY : v;
        float m2 = vm; int i2 = e;
#pragma unroll
        for (int sh = 32; sh > 0; sh >>= 1) {
            float ov = __shfl_xor(m2, sh, 64);
            int   oi = __shfl_xor(i2, sh, 64);
            if (ov > m2 || (ov == m2 && oi < i2)) { m2 = ov; i2 = oi; }
        }

        const float e2  = expf(m2 - m1);
        const float inv = 1.f / (1.f + e2);
        const float p1  = inv;
        const float p2  = e2 * inv;

        float gval = 0.f;
        if (e == i1) gval = p1;
        else if (e == i2) gval = p2;
        out[(size_t)tok * NEXP + e] = gval;

        if (lane == 0) {
            out[IDX_OFF  + tok * 2 + 0] = (float)i1;
            out[IDX_OFF  + tok * 2 + 1] = (float)i2;
            out[VALS_OFF + tok * 2 + 0] = m1;
            out[VALS_OFF + tok * 2 + 1] = m2;
        }
    }
}

extern "C" void kernel_launch(void* const* d_in, const int* in_sizes, int n_in,
                              void* d_out, int out_size, void* d_ws, size_t ws_size,
                              hipStream_t stream) {
    const float* x     = (const float*)d_in[0];
    const float* W     = (const float*)d_in[1];
    const float* nw    = (const float*)d_in[2];
    const float* noise = (const float*)d_in[3];
    // d_in[4] is k==2, hardcoded
    float* out = (float*)d_out;

    _Float16* Bh = (_Float16*)d_ws;                 // 256 KB
    _Float16* Bl = Bh + BFRAG_HALVES;               // 256 KB

    hipLaunchKernelGGL(pack_b_kernel, dim3(64), dim3(256), 0, stream, W, Bh, Bl);

    hipLaunchKernelGGL(gate_kernel, dim3(NTOK / MT), dim3(512), 0, stream,
                       x, Bh, Bl, nw, noise, out);
}